// Round 20
// baseline (117.060 us; speedup 1.0000x reference)
//
#include <hip/hip_runtime.h>
#include <math.h>

#define N_PIX 8192      // 2*64*64
#define D 64
#define HW 4096         // h*w
#define BSTRIDE 262144  // d*h*w
#define C1 14.4269504088896340736f   // 10 * log2(e)
#define LN2 0.6931471805599453f
#define NSEG 32
#define SEGCOLS 256
#define BC 256

typedef __attribute__((ext_vector_type(8))) short short8;   // 8 bf16 = 4 VGPR
typedef __attribute__((ext_vector_type(4))) float f32x4;

#define LDS_AS __attribute__((address_space(3)))
#define GLB_AS __attribute__((address_space(1)))

__device__ inline ushort f2bf(float x) {   // fp32 -> bf16 RNE
    uint u = __float_as_uint(x);
    return (ushort)((u + 0x7FFFu + ((u >> 16) & 1u)) >> 16);
}

// async 16B global->LDS (dest = wave-uniform base + lane*16)
__device__ inline void gll16(const ushort* g, ushort* l) {
    __builtin_amdgcn_global_load_lds((const GLB_AS uint*)g, (LDS_AS uint*)l, 16, 0, 0);
}

// Stage BC cols x 64 ch bf16 into LDS, XOR-swizzled (verified r8-r19).
__device__ inline void stage(const ushort* __restrict__ z2b, int jcol,
                             ushort* ldsbuf, int wave, int lane) {
    int l3 = lane >> 3, l7 = lane & 7;
    int xo = (l7 ^ l3) << 3;     // ushort offset of swizzled 16B slot
#pragma unroll
    for (int q = 0; q < BC / 32; ++q) {
        int c = wave * (BC / 32) + q;
        const ushort* src = z2b + (size_t)(jcol + c * 8 + l3) * D + xo;
        gll16(src, ldsbuf + c * 512);
    }
}

// ---------- K1: transpose + L2-normalize; 8 threads/pixel; z1 pre-scaled by C1 ----------
__global__ __launch_bounds__(256) void knorm(const float* __restrict__ z1,
                                             const float* __restrict__ z2,
                                             ushort* __restrict__ z1b,
                                             ushort* __restrict__ z2b,
                                             float* __restrict__ out) {
    int gid = blockIdx.x * 256 + threadIdx.x;   // 0..131071
    if (gid == 0) out[0] = 0.f;                 // fold memset (kfinal accumulates later)
    int q = gid & 7;                             // 8-channel group
    int pixg = gid >> 3;                         // 0..16383
    int t = pixg >> 13;
    int n = pixg & (N_PIX - 1);
    const float* src = t ? z2 : z1;
    ushort* dst = t ? z2b : z1b;
    int b = n >> 12;
    int p = n & 4095;
    const float* base = src + b * BSTRIDE + (q * 8) * HW + p;
    float v[8];
    float ss = 0.f;
#pragma unroll
    for (int c = 0; c < 8; ++c) { v[c] = base[(size_t)c * HW]; ss = fmaf(v[c], v[c], ss); }
    ss += __shfl_xor(ss, 1);                     // 8-lane group shares pixel
    ss += __shfl_xor(ss, 2);
    ss += __shfl_xor(ss, 4);
    float inv = 1.0f / fmaxf(sqrtf(ss), 1e-12f);
    float sc = t ? inv : inv * C1;               // bake 10*log2(e) into z1 rows
    uint4 w;
#pragma unroll
    for (int j = 0; j < 4; ++j) {
        ((uint*)&w)[j] = (uint)f2bf(v[2 * j] * sc) | ((uint)f2bf(v[2 * j + 1] * sc) << 16);
    }
    *(uint4*)(dst + (size_t)n * D + q * 8) = w;
}

// ---------- K2: MFMA sim + bare exp2; 2-bank shifted pipeline + free diag ----------
// block = 4 waves x 64 rows = 256 rows x 256 cols; grid (32, 32) = 1024 blocks = 4/CU.
// acc = C1*dot (z1 pre-scaled). Pipeline: MFMAs of ct+1 issue before exp2 of ct.
__global__ __launch_bounds__(256, 4) void ksim(const ushort* __restrict__ z1b,
                                               const ushort* __restrict__ z2b,
                                               float* __restrict__ ps,
                                               float* __restrict__ diag) {
    __shared__ ushort lds[BC * D];   // 32KB
    int tid = threadIdx.x;
    int wave = tid >> 6, lane = tid & 63;
    int lrow = lane & 15;        // A-row / B-col within 16
    int lk = lane >> 4;          // k-chunk 0..3
    int rbase = blockIdx.x * 256 + wave * 64;
    int jbase = blockIdx.y * SEGCOLS;

    stage(z2b, jbase, lds, wave, lane);          // 8 async 1KB chunks per wave

    // A fragments: 4 row-tiles x 2 k-halves
    const ushort* ar = z1b + (size_t)(rbase + lrow) * D + lk * 8;
    short8 a0[4], a1[4];
#pragma unroll
    for (int rt = 0; rt < 4; ++rt) {
        a0[rt] = *(const short8*)(ar + rt * 16 * D);
        a1[rt] = *(const short8*)(ar + rt * 16 * D + 32);
    }

    float s[16];
#pragma unroll
    for (int i = 0; i < 16; ++i) s[i] = 0.f;

    __syncthreads();                             // drain staging, once

    const char* bb = (const char*)lds;
    int sw = (lrow & 7);
    bool dblk = (blockIdx.x == blockIdx.y);
    f32x4 z = {0.f, 0.f, 0.f, 0.f};
    f32x4 accA[4], accB[4];

// compute acc bank for one ct (2 ds_read + 8 MFMA) + predicated diag capture
#define ACCBLK(BANK, CT)                                                            \
    {                                                                               \
        int rowoff = ((CT) * 16 + lrow) << 7;                                       \
        short8 blo = *(const short8*)(bb + rowoff + ((lk ^ sw) << 4));              \
        short8 bhi = *(const short8*)(bb + rowoff + (((4 + lk) ^ sw) << 4));        \
        _Pragma("unroll")                                                           \
        for (int rt = 0; rt < 4; ++rt) {                                            \
            f32x4 t0 = __builtin_amdgcn_mfma_f32_16x16x32_bf16(a0[rt], blo, z, 0, 0, 0); \
            BANK[rt] = __builtin_amdgcn_mfma_f32_16x16x32_bf16(a1[rt], bhi, t0, 0, 0, 0); \
            if (dblk && (CT) == wave * 4 + rt && (lrow >> 2) == lk) {               \
                int rr = lrow & 3;                                                  \
                float dv = rr == 0 ? BANK[rt][0] : (rr == 1 ? BANK[rt][1] :         \
                           (rr == 2 ? BANK[rt][2] : BANK[rt][3]));                  \
                diag[rbase + rt * 16 + lrow] = dv;                                  \
            }                                                                       \
        }                                                                           \
    }
#define EXPBLK(BANK)                                                                \
    _Pragma("unroll")                                                               \
    for (int rt = 0; rt < 4; ++rt) {                                                \
        _Pragma("unroll")                                                           \
        for (int r = 0; r < 4; ++r)                                                 \
            s[rt * 4 + r] += __builtin_amdgcn_exp2f(BANK[rt][r]);                   \
    }

    ACCBLK(accA, 0)
#pragma unroll
    for (int c2 = 0; c2 < 7; ++c2) {
        ACCBLK(accB, 2 * c2 + 1)    // MFMAs for ct+1 in flight...
        EXPBLK(accA)                // ...while TRANS handles ct
        ACCBLK(accA, 2 * c2 + 2)
        EXPBLK(accB)
    }
    ACCBLK(accB, 15)
    EXPBLK(accA)
    EXPBLK(accB)
#undef ACCBLK
#undef EXPBLK

    // reduce over 16 lanes sharing lk (different cols, same rows)
#pragma unroll
    for (int off = 1; off <= 8; off <<= 1) {
#pragma unroll
        for (int i = 0; i < 16; ++i) s[i] += __shfl_xor(s[i], off);
    }
    if (lrow == 0) {
        int seg = blockIdx.y;
#pragma unroll
        for (int rt = 0; rt < 4; ++rt)
#pragma unroll
            for (int r = 0; r < 4; ++r)
                ps[(size_t)(rbase + rt * 16 + lk * 4 + r) * NSEG + seg] = s[rt * 4 + r];
    }
}

// ---------- K3: ps-sum + diag -> mean (no z reads) ----------
__global__ __launch_bounds__(64) void kfinal(const float* __restrict__ ps,
                                             const float* __restrict__ diag,
                                             float* __restrict__ out) {
    int tid = threadIdx.x;
    int row = blockIdx.x * 64 + tid;

    const f32x4* pp = (const f32x4*)(ps + (size_t)row * NSEG);
    float s = 0.f;
#pragma unroll
    for (int q = 0; q < NSEG / 4; ++q) {
        f32x4 v = pp[q];
        s += (v[0] + v[1]) + (v[2] + v[3]);
    }
    float val = __logf(s) - LN2 * diag[row];     // diag already = C1*dot

#pragma unroll
    for (int off = 32; off > 0; off >>= 1) val += __shfl_down(val, off);
    if (tid == 0) atomicAdd(out, val * (1.0f / (float)N_PIX));
}

extern "C" void kernel_launch(void* const* d_in, const int* in_sizes, int n_in,
                              void* d_out, int out_size, void* d_ws, size_t ws_size,
                              hipStream_t stream) {
    const float* z1 = (const float*)d_in[0];
    const float* z2 = (const float*)d_in[1];
    float* out = (float*)d_out;

    ushort* z1b = (ushort*)d_ws;                        // 1 MB
    ushort* z2b = z1b + (size_t)N_PIX * D;              // 1 MB
    float* ps   = (float*)(z2b + (size_t)N_PIX * D);    // 1 MB
    float* diag = ps + (size_t)N_PIX * NSEG;            // 32 KB

    knorm<<<512, 256, 0, stream>>>(z1, z2, z1b, z2b, out);
    dim3 g2(N_PIX / 256, NSEG);                         // (32, 32) = 1024 blocks
    ksim<<<g2, 256, 0, stream>>>(z1b, z2b, ps, diag);
    kfinal<<<N_PIX / 64, 64, 0, stream>>>(ps, diag, out);
}

// Round 21
// 26.620 us; speedup vs baseline: 4.3974x; 4.3974x over previous
//
#include <hip/hip_runtime.h>
#include <math.h>

#define N_PIX 8192      // 2*64*64
#define D 64
#define HW 4096         // h*w
#define BSTRIDE 262144  // d*h*w
#define C1 14.4269504088896340736f   // 10 * log2(e)
#define LN2 0.6931471805599453f
#define NSEG 32
#define SEGCOLS 256
#define BC 256

typedef __attribute__((ext_vector_type(8))) short short8;   // 8 bf16 = 4 VGPR
typedef __attribute__((ext_vector_type(4))) float f32x4;

#define LDS_AS __attribute__((address_space(3)))
#define GLB_AS __attribute__((address_space(1)))

__device__ inline ushort f2bf(float x) {   // fp32 -> bf16 RNE
    uint u = __float_as_uint(x);
    return (ushort)((u + 0x7FFFu + ((u >> 16) & 1u)) >> 16);
}
__device__ inline float bflo(uint u) { return __uint_as_float(u << 16); }
__device__ inline float bfhi(uint u) { return __uint_as_float(u & 0xFFFF0000u); }

// async 16B global->LDS (dest = wave-uniform base + lane*16)
__device__ inline void gll16(const ushort* g, ushort* l) {
    __builtin_amdgcn_global_load_lds((const GLB_AS uint*)g, (LDS_AS uint*)l, 16, 0, 0);
}

// Stage BC cols x 64 ch bf16 into LDS, XOR-swizzled (verified r8-r20).
__device__ inline void stage(const ushort* __restrict__ z2b, int jcol,
                             ushort* ldsbuf, int wave, int lane) {
    int l3 = lane >> 3, l7 = lane & 7;
    int xo = (l7 ^ l3) << 3;     // ushort offset of swizzled 16B slot
#pragma unroll
    for (int q = 0; q < BC / 32; ++q) {
        int c = wave * (BC / 32) + q;
        const ushort* src = z2b + (size_t)(jcol + c * 8 + l3) * D + xo;
        gll16(src, ldsbuf + c * 512);
    }
}

// ---------- K1: transpose + L2-normalize; 8 threads/pixel; z1 pre-scaled by C1 ----------
__global__ __launch_bounds__(256) void knorm(const float* __restrict__ z1,
                                             const float* __restrict__ z2,
                                             ushort* __restrict__ z1b,
                                             ushort* __restrict__ z2b,
                                             float* __restrict__ out) {
    int gid = blockIdx.x * 256 + threadIdx.x;   // 0..131071
    if (gid == 0) out[0] = 0.f;                 // fold memset (kfinal accumulates later)
    int q = gid & 7;                             // 8-channel group
    int pixg = gid >> 3;                         // 0..16383
    int t = pixg >> 13;
    int n = pixg & (N_PIX - 1);
    const float* src = t ? z2 : z1;
    ushort* dst = t ? z2b : z1b;
    int b = n >> 12;
    int p = n & 4095;
    const float* base = src + b * BSTRIDE + (q * 8) * HW + p;
    float v[8];
    float ss = 0.f;
#pragma unroll
    for (int c = 0; c < 8; ++c) { v[c] = base[(size_t)c * HW]; ss = fmaf(v[c], v[c], ss); }
    ss += __shfl_xor(ss, 1);                     // 8-lane group shares pixel
    ss += __shfl_xor(ss, 2);
    ss += __shfl_xor(ss, 4);
    float inv = 1.0f / fmaxf(sqrtf(ss), 1e-12f);
    float sc = t ? inv : inv * C1;               // bake 10*log2(e) into z1 rows
    uint4 w;
#pragma unroll
    for (int j = 0; j < 4; ++j) {
        ((uint*)&w)[j] = (uint)f2bf(v[2 * j] * sc) | ((uint)f2bf(v[2 * j + 1] * sc) << 16);
    }
    *(uint4*)(dst + (size_t)n * D + q * 8) = w;
}

// ---------- K2: MFMA sim + bare exp2; 32 rows/wave 2-bank pipeline (fits 64 VGPR) ----
// block = 4 waves x 32 rows = 128 rows x 256 cols; grid (64, 32) = 2048 blocks.
// LDS 32KB -> 5 blocks/CU. ACC(ct+1) issues before EXP(ct): MFMA pipe overlaps TRANS.
__global__ __launch_bounds__(256, 4) void ksim(const ushort* __restrict__ z1b,
                                               const ushort* __restrict__ z2b,
                                               float* __restrict__ ps) {
    __shared__ ushort lds[BC * D];   // 32KB
    int tid = threadIdx.x;
    int wave = tid >> 6, lane = tid & 63;
    int lrow = lane & 15;        // A-row / B-col within 16
    int lk = lane >> 4;          // k-chunk 0..3
    int rbase = blockIdx.x * 128 + wave * 32;
    int jbase = blockIdx.y * SEGCOLS;

    stage(z2b, jbase, lds, wave, lane);          // 8 async 1KB chunks per wave

    // A fragments: 2 row-tiles x 2 k-halves = 16 VGPR
    const ushort* ar = z1b + (size_t)(rbase + lrow) * D + lk * 8;
    short8 a0[2], a1[2];
#pragma unroll
    for (int rt = 0; rt < 2; ++rt) {
        a0[rt] = *(const short8*)(ar + rt * 16 * D);
        a1[rt] = *(const short8*)(ar + rt * 16 * D + 32);
    }

    float s[8];
#pragma unroll
    for (int i = 0; i < 8; ++i) s[i] = 0.f;

    __syncthreads();                             // drain staging, once

    const char* bb = (const char*)lds;
    int sw = (lrow & 7);
    f32x4 z = {0.f, 0.f, 0.f, 0.f};
    f32x4 accA[2], accB[2];

#define ACCBLK(BANK, CT)                                                            \
    {                                                                               \
        int rowoff = ((CT) * 16 + lrow) << 7;                                       \
        short8 blo = *(const short8*)(bb + rowoff + ((lk ^ sw) << 4));              \
        short8 bhi = *(const short8*)(bb + rowoff + (((4 + lk) ^ sw) << 4));        \
        _Pragma("unroll")                                                           \
        for (int rt = 0; rt < 2; ++rt) {                                            \
            f32x4 t0 = __builtin_amdgcn_mfma_f32_16x16x32_bf16(a0[rt], blo, z, 0, 0, 0); \
            BANK[rt] = __builtin_amdgcn_mfma_f32_16x16x32_bf16(a1[rt], bhi, t0, 0, 0, 0); \
        }                                                                           \
    }
#define EXPBLK(BANK)                                                                \
    _Pragma("unroll")                                                               \
    for (int rt = 0; rt < 2; ++rt) {                                                \
        _Pragma("unroll")                                                           \
        for (int r = 0; r < 4; ++r)                                                 \
            s[rt * 4 + r] += __builtin_amdgcn_exp2f(BANK[rt][r]);                   \
    }

    ACCBLK(accA, 0)
#pragma unroll
    for (int c2 = 0; c2 < 7; ++c2) {
        ACCBLK(accB, 2 * c2 + 1)    // MFMAs for ct+1 in flight...
        EXPBLK(accA)                // ...while TRANS handles ct
        ACCBLK(accA, 2 * c2 + 2)
        EXPBLK(accB)
    }
    ACCBLK(accB, 15)
    EXPBLK(accA)
    EXPBLK(accB)
#undef ACCBLK
#undef EXPBLK

    // reduce over 16 lanes sharing lk (different cols, same rows)
#pragma unroll
    for (int off = 1; off <= 8; off <<= 1) {
#pragma unroll
        for (int i = 0; i < 8; ++i) s[i] += __shfl_xor(s[i], off);
    }
    if (lrow == 0) {
        int seg = blockIdx.y;
#pragma unroll
        for (int rt = 0; rt < 2; ++rt)
#pragma unroll
            for (int r = 0; r < 4; ++r)
                ps[(size_t)(rbase + rt * 16 + lk * 4 + r) * NSEG + seg] = s[rt * 4 + r];
    }
}

// ---------- K3: combine partials + diag dot + mean via atomic (r19 version) ----------
__global__ __launch_bounds__(64) void kfinal(const ushort* __restrict__ z1b,
                                             const ushort* __restrict__ z2b,
                                             const float* __restrict__ ps,
                                             float* __restrict__ out) {
    int tid = threadIdx.x;
    int row = blockIdx.x * 64 + tid;

    const f32x4* pp = (const f32x4*)(ps + (size_t)row * NSEG);
    float s = 0.f;
#pragma unroll
    for (int q = 0; q < NSEG / 4; ++q) {
        f32x4 v = pp[q];
        s += (v[0] + v[1]) + (v[2] + v[3]);
    }
    const uint4* xp = (const uint4*)(z1b + (size_t)row * D);
    const uint4* yp = (const uint4*)(z2b + (size_t)row * D);
    float d = 0.f;
#pragma unroll
    for (int q = 0; q < 8; ++q) {
        uint4 x = xp[q], y = yp[q];
        d = fmaf(bflo(x.x), bflo(y.x), d); d = fmaf(bfhi(x.x), bfhi(y.x), d);
        d = fmaf(bflo(x.y), bflo(y.y), d); d = fmaf(bfhi(x.y), bfhi(y.y), d);
        d = fmaf(bflo(x.z), bflo(y.z), d); d = fmaf(bfhi(x.z), bfhi(y.z), d);
        d = fmaf(bflo(x.w), bflo(y.w), d); d = fmaf(bfhi(x.w), bfhi(y.w), d);
    }
    float val = __logf(s) - LN2 * d;             // d = C1*dot (z1b pre-scaled)

#pragma unroll
    for (int off = 32; off > 0; off >>= 1) val += __shfl_down(val, off);
    if (tid == 0) atomicAdd(out, val * (1.0f / (float)N_PIX));
}

extern "C" void kernel_launch(void* const* d_in, const int* in_sizes, int n_in,
                              void* d_out, int out_size, void* d_ws, size_t ws_size,
                              hipStream_t stream) {
    const float* z1 = (const float*)d_in[0];
    const float* z2 = (const float*)d_in[1];
    float* out = (float*)d_out;

    ushort* z1b = (ushort*)d_ws;                        // 1 MB
    ushort* z2b = z1b + (size_t)N_PIX * D;              // 1 MB
    float* ps   = (float*)(z2b + (size_t)N_PIX * D);    // 1 MB

    knorm<<<512, 256, 0, stream>>>(z1, z2, z1b, z2b, out);
    dim3 g2(N_PIX / 128, NSEG);                         // (64, 32) = 2048 blocks
    ksim<<<g2, 256, 0, stream>>>(z1b, z2b, ps);
    kfinal<<<N_PIX / 64, 64, 0, stream>>>(z1b, z2b, ps, out);
}